// Round 1
// baseline (372.822 us; speedup 1.0000x reference)
//
#include <hip/hip_runtime.h>
#include <hip/hip_bf16.h>
#include <stdint.h>

namespace {

constexpr int B = 8, T = 200, U = 50, D = 512, INNER = 640, VOCAB = 1024;
constexpr int M_TOTAL = B * T * U;          // 80000
constexpr int ROWS_E = B * T;               // 1600
constexpr int ROWS_D = B * U;               // 400
constexpr int ROWS_ED = ROWS_E + ROWS_D;    // 2000

typedef __bf16 bf16x8 __attribute__((ext_vector_type(8)));
typedef float  f32x4  __attribute__((ext_vector_type(4)));
typedef unsigned short u16;

__device__ __forceinline__ u16 f2bf(float f) {
  uint32_t u = __float_as_uint(f);
  uint32_t rounding = 0x7FFFu + ((u >> 16) & 1u);   // round-to-nearest-even
  return (u16)((u + rounding) >> 16);
}

__device__ __forceinline__ float fast_tanh(float x) {
  // tanh(x) = 1 - 2/(exp(2x)+1); safe at both infinities
  float e = __expf(2.0f * x);
  float r = __builtin_amdgcn_rcpf(e + 1.0f);
  return 1.0f - 2.0f * r;
}

// ---------------------------------------------------------------------------
// Kernel 1: ED[0:1600]  = enc @ W1 + b1   (fp32)
//           ED[1600:2000] = dec @ W1      (fp32, b1 folded into enc part only)
// grid 250 blocks x 320 threads, 8 rows per block (1600 % 8 == 0 -> uniform)
// ---------------------------------------------------------------------------
__global__ __launch_bounds__(320) void k_ed(const float* __restrict__ enc,
                                            const float* __restrict__ dec,
                                            const float* __restrict__ W1,
                                            const float* __restrict__ b1,
                                            float* __restrict__ ED) {
  __shared__ float rows[8 * D];   // 16 KiB
  const int r0 = blockIdx.x * 8;
  const bool is_enc = (r0 < ROWS_E);
  const float* src = is_enc ? (enc + (size_t)r0 * D)
                            : (dec + (size_t)(r0 - ROWS_E) * D);
  for (int i = threadIdx.x; i < 8 * D; i += 320) rows[i] = src[i];
  __syncthreads();

  const int c0 = threadIdx.x, c1 = threadIdx.x + 320;
  float acc[8][2];
  const float bias0 = is_enc ? b1[c0] : 0.f;
  const float bias1 = is_enc ? b1[c1] : 0.f;
#pragma unroll
  for (int r = 0; r < 8; ++r) { acc[r][0] = bias0; acc[r][1] = bias1; }

  for (int d = 0; d < D; d += 4) {
    float4 rv[8];
#pragma unroll
    for (int r = 0; r < 8; ++r)
      rv[r] = *reinterpret_cast<const float4*>(&rows[r * D + d]);
#pragma unroll
    for (int dd = 0; dd < 4; ++dd) {
      const float w0 = W1[(size_t)(d + dd) * INNER + c0];
      const float w1 = W1[(size_t)(d + dd) * INNER + c1];
#pragma unroll
      for (int r = 0; r < 8; ++r) {
        const float x = (dd == 0) ? rv[r].x : (dd == 1) ? rv[r].y
                        : (dd == 2) ? rv[r].z : rv[r].w;
        acc[r][0] = fmaf(x, w0, acc[r][0]);
        acc[r][1] = fmaf(x, w1, acc[r][1]);
      }
    }
  }
#pragma unroll
  for (int r = 0; r < 8; ++r) {
    ED[(size_t)(r0 + r) * INNER + c0] = acc[r][0];
    ED[(size_t)(r0 + r) * INNER + c1] = acc[r][1];
  }
}

// ---------------------------------------------------------------------------
// Kernel 2: W2T[n][k] = bf16(W2[k][n])   (1024 x 640 bf16)
// ---------------------------------------------------------------------------
__global__ void k_w2t(const float* __restrict__ W2, u16* __restrict__ W2T) {
  const int idx = blockIdx.x * blockDim.x + threadIdx.x;
  if (idx >= INNER * VOCAB) return;
  const int k = idx / VOCAB;
  const int n = idx - k * VOCAB;          // consecutive tid -> consecutive n (coalesced read)
  W2T[(size_t)n * INNER + k] = f2bf(W2[idx]);
}

// ---------------------------------------------------------------------------
// Kernel 3: fused  out[m][n] = tanh(E1[t(m)] + D1[u(m)]) @ W2 + b2
// tile 128(M) x 256(N), BK=64, 8 waves (2Mx4N), 512 threads
// grid (625, 4); no tails: 80000/128=625, 1024/256=4, 640/64=10
// ---------------------------------------------------------------------------
__global__ __launch_bounds__(512) void k_main(const float* __restrict__ ED,
                                              const u16* __restrict__ W2T,
                                              const float* __restrict__ b2,
                                              float* __restrict__ out) {
  __shared__ u16 hid[128 * 64];     // 16 KiB, XOR-swizzled: byte ^= (row&7)<<4
  __shared__ int rowE_s[128];
  __shared__ int rowD_s[128];

  const int m0 = blockIdx.x * 128;
  const int n0 = blockIdx.y * 256;
  const int tid = threadIdx.x;

  if (tid < 128) {
    const int m = m0 + tid;
    const int b = m / (T * U);
    const int rem = m - b * (T * U);
    const int t = rem / U;
    const int u = rem - t * U;
    rowE_s[tid] = b * T + t;
    rowD_s[tid] = ROWS_E + b * U + u;
  }

  const int lane = tid & 63;
  const int w   = tid >> 6;     // 0..7
  const int wr  = w >> 2;       // 0..1
  const int wc  = w & 3;        // 0..3
  const int lhi = lane >> 4;    // 0..3
  const int llo = lane & 15;    // 0..15

  f32x4 acc[4][4];
#pragma unroll
  for (int i = 0; i < 4; ++i)
#pragma unroll
    for (int j = 0; j < 4; ++j) acc[i][j] = (f32x4){0.f, 0.f, 0.f, 0.f};

  // hidden-compute mapping: 4 consecutive k per thread
  const int hr = tid >> 4;            // 0..31 (+32 per it)
  const int hk = (tid & 15) * 4;      // 0..60

  char* hid_b = reinterpret_cast<char*>(hid);

  __syncthreads();   // rowE_s/rowD_s ready

  for (int kc = 0; kc < INNER; kc += 64) {
    // ---- hidden tile: 128 rows x 64 k, bf16, swizzled ----
#pragma unroll
    for (int it = 0; it < 4; ++it) {
      const int r = hr + it * 32;
      const int re = rowE_s[r];
      const int rd = rowD_s[r];
      const float4 e  = *reinterpret_cast<const float4*>(&ED[(size_t)re * INNER + kc + hk]);
      const float4 dv = *reinterpret_cast<const float4*>(&ED[(size_t)rd * INNER + kc + hk]);
      const u16 h0 = f2bf(fast_tanh(e.x + dv.x));
      const u16 h1 = f2bf(fast_tanh(e.y + dv.y));
      const u16 h2 = f2bf(fast_tanh(e.z + dv.z));
      const u16 h3 = f2bf(fast_tanh(e.w + dv.w));
      const uint64_t pack = (uint64_t)h0 | ((uint64_t)h1 << 16) |
                            ((uint64_t)h2 << 32) | ((uint64_t)h3 << 48);
      int byte = r * 128 + hk * 2;
      byte ^= (r & 7) << 4;
      *reinterpret_cast<uint64_t*>(hid_b + byte) = pack;
    }
    __syncthreads();   // hidden ready

    // ---- MFMA: two K=32 sub-steps ----
#pragma unroll
    for (int ks = 0; ks < 64; ks += 32) {
      bf16x8 a[4], bfr[4];
#pragma unroll
      for (int mi = 0; mi < 4; ++mi) {
        const int r = wr * 64 + mi * 16 + llo;
        int byte = r * 128 + (ks + lhi * 8) * 2;
        byte ^= (r & 7) << 4;
        a[mi] = *reinterpret_cast<const bf16x8*>(hid_b + byte);
      }
#pragma unroll
      for (int ni = 0; ni < 4; ++ni) {
        const int n = n0 + wc * 64 + ni * 16 + llo;
        bfr[ni] = *reinterpret_cast<const bf16x8*>(&W2T[(size_t)n * INNER + kc + ks + lhi * 8]);
      }
#pragma unroll
      for (int mi = 0; mi < 4; ++mi)
#pragma unroll
        for (int ni = 0; ni < 4; ++ni)
          acc[mi][ni] = __builtin_amdgcn_mfma_f32_16x16x32_bf16(a[mi], bfr[ni], acc[mi][ni], 0, 0, 0);
    }
    __syncthreads();   // protect hid before next overwrite
  }

  // ---- epilogue: out = acc + b2 ----
#pragma unroll
  for (int ni = 0; ni < 4; ++ni) {
    const int col = n0 + wc * 64 + ni * 16 + llo;
    const float bias = b2[col];
#pragma unroll
    for (int mi = 0; mi < 4; ++mi) {
      const int row = m0 + wr * 64 + mi * 16 + lhi * 4;
#pragma unroll
      for (int q = 0; q < 4; ++q) {
        out[(size_t)(row + q) * VOCAB + col] = acc[mi][ni][q] + bias;
      }
    }
  }
}

}  // namespace

extern "C" void kernel_launch(void* const* d_in, const int* in_sizes, int n_in,
                              void* d_out, int out_size, void* d_ws, size_t ws_size,
                              hipStream_t stream) {
  const float* enc = (const float*)d_in[0];
  const float* dec = (const float*)d_in[1];
  const float* W1  = (const float*)d_in[2];
  const float* b1  = (const float*)d_in[3];
  const float* W2  = (const float*)d_in[4];
  const float* b2  = (const float*)d_in[5];
  float* out = (float*)d_out;

  float* ED  = (float*)d_ws;                                        // 2000*640*4 = 5,120,000 B
  u16*   W2T = (u16*)((char*)d_ws + (size_t)ROWS_ED * INNER * 4);   // 1024*640*2 = 1,310,720 B

  hipLaunchKernelGGL(k_ed, dim3(ROWS_ED / 8), dim3(320), 0, stream,
                     enc, dec, W1, b1, ED);
  hipLaunchKernelGGL(k_w2t, dim3((INNER * VOCAB + 255) / 256), dim3(256), 0, stream,
                     W2, W2T);
  hipLaunchKernelGGL(k_main, dim3(M_TOTAL / 128, VOCAB / 256), dim3(512), 0, stream,
                     ED, W2T, b2, out);
}